// Round 1
// baseline (2127.832 us; speedup 1.0000x reference)
//
#include <hip/hip_runtime.h>
#include <math.h>

// Channel attention (XCA-style), fp32 correctness-first baseline.
// b=8, c=256, H=W=128, heads=8, d=32, ps=4 -> nh=nw=32, e=16.
// Pipeline: K1 qkv = W_qkv @ x  (GEMM M=768,K=256,N=pix)
//           K2 depthwise3x3 + window + l2norm + 32x32 channel-attn + PV
//           K3 out = W_proj @ attn_out (GEMM M=256,K=256,N=pix)

#define HW_ (128*128)
#define CHW_ (256*128*128)

// Generic fp32 GEMM, K fixed = 256. C[m,n] = sum_k A[m*256+k] * B[k*ldb+n].
// M given by gridDim.y*64 (must divide), N = gridDim.x*64.
__global__ __launch_bounds__(256) void gemm_f32_k256(
    const float* __restrict__ A,   // [M][256] row-major
    const float* __restrict__ Bp,  // (k,n) at Bp[k*ldb + n]
    float* __restrict__ Cp,        // (m,n) at Cp[m*ldc + n]
    int ldb, int ldc)
{
    __shared__ float As[64][17];   // [m][k], padded
    __shared__ float Bs[16][64];   // [k][n]
    const int t  = threadIdx.x;
    const int tx = t & 15;         // n/4
    const int ty = t >> 4;         // m/4
    const int m0 = blockIdx.y * 64;
    const int n0 = blockIdx.x * 64;

    float acc[4][4];
    #pragma unroll
    for (int i = 0; i < 4; ++i)
        #pragma unroll
        for (int j = 0; j < 4; ++j) acc[i][j] = 0.f;

    for (int k0 = 0; k0 < 256; k0 += 16) {
        // stage A tile: 64x16
        #pragma unroll
        for (int i = 0; i < 4; ++i) {
            int idx = t + i * 256;          // 0..1023
            int k = idx & 15, m = idx >> 4;
            As[m][k] = A[(m0 + m) * 256 + k0 + k];
        }
        // stage B tile: 16x64 via float4
        {
            int k = t >> 4, n = (t & 15) * 4;
            const float4 v = *reinterpret_cast<const float4*>(
                Bp + (size_t)(k0 + k) * ldb + n0 + n);
            Bs[k][n + 0] = v.x; Bs[k][n + 1] = v.y;
            Bs[k][n + 2] = v.z; Bs[k][n + 3] = v.w;
        }
        __syncthreads();
        #pragma unroll
        for (int k = 0; k < 16; ++k) {
            float a0 = As[ty * 4 + 0][k];
            float a1 = As[ty * 4 + 1][k];
            float a2 = As[ty * 4 + 2][k];
            float a3 = As[ty * 4 + 3][k];
            float4 b = *reinterpret_cast<const float4*>(&Bs[k][tx * 4]);
            acc[0][0] += a0 * b.x; acc[0][1] += a0 * b.y; acc[0][2] += a0 * b.z; acc[0][3] += a0 * b.w;
            acc[1][0] += a1 * b.x; acc[1][1] += a1 * b.y; acc[1][2] += a1 * b.z; acc[1][3] += a1 * b.w;
            acc[2][0] += a2 * b.x; acc[2][1] += a2 * b.y; acc[2][2] += a2 * b.z; acc[2][3] += a2 * b.w;
            acc[3][0] += a3 * b.x; acc[3][1] += a3 * b.y; acc[3][2] += a3 * b.z; acc[3][3] += a3 * b.w;
        }
        __syncthreads();
    }
    #pragma unroll
    for (int i = 0; i < 4; ++i) {
        float4 v = make_float4(acc[i][0], acc[i][1], acc[i][2], acc[i][3]);
        *reinterpret_cast<float4*>(Cp + (size_t)(m0 + ty * 4 + i) * ldc + n0 + tx * 4) = v;
    }
}

// One block = one 4x4 window x 2 heads. Stages 6x6 halo of 192 qkv channels,
// depthwise 3x3, l2norm(q,k) over e=16, 32x32 channel attention, PV.
__global__ __launch_bounds__(256) void attn_win(
    const float* __restrict__ qkv,   // [768][Nh], rows [r0h, r1h) of image
    const float* __restrict__ Wdw,   // [768][9]
    const float* __restrict__ temp,  // [8]
    float* __restrict__ attnout,     // [256][NR], rows [r0, ...)
    int r0, int r0h, int Nh, int NR)
{
    __shared__ float halo[192 * 37]; // [ch][36] padded to 37
    __shared__ float dwv[192 * 17];  // [ch][16] padded to 17

    const int t  = threadIdx.x;
    const int iw = blockIdx.x;
    const int ih = (r0 >> 2) + blockIdx.y;
    const int h0 = blockIdx.z * 2;   // first head of the pair

    // ---- stage 6x6 halo of the 192 channels this head-pair needs ----
    for (int idx = t; idx < 192 * 36; idx += 256) {
        int ch  = idx / 36;
        int pos = idx - ch * 36;
        int hy = pos / 6, hx = pos - hy * 6;
        int gy = ih * 4 + hy - 1;
        int gx = iw * 4 + hx - 1;
        int sec = ch >> 6;                       // 0=q,1=k,2=v
        int gch = sec * 256 + h0 * 32 + (ch & 63);
        float v = 0.f;
        if (gy >= 0 && gy < 128 && gx >= 0 && gx < 128)
            v = qkv[(size_t)gch * Nh + (gy - r0h) * 128 + gx];
        halo[ch * 37 + pos] = v;
    }
    __syncthreads();

    // ---- depthwise 3x3 (cross-correlation, SAME/zero-pad) ----
    for (int idx = t; idx < 192 * 16; idx += 256) {
        int ch = idx >> 4, p = idx & 15;
        int ph = p >> 2, pw = p & 3;
        int sec = ch >> 6;
        int gch = sec * 256 + h0 * 32 + (ch & 63);
        const float* wp = Wdw + gch * 9;
        float s = 0.f;
        #pragma unroll
        for (int dy = 0; dy < 3; ++dy)
            #pragma unroll
            for (int dx = 0; dx < 3; ++dx)
                s += halo[ch * 37 + (ph + dy) * 6 + (pw + dx)] * wp[dy * 3 + dx];
        dwv[ch * 17 + p] = s;
    }
    __syncthreads();

    // ---- l2norm q (local rows 0..63) and k (64..127) over e ----
    if (t < 128) {
        float s = 0.f;
        #pragma unroll
        for (int e = 0; e < 16; ++e) { float v = dwv[t * 17 + e]; s += v * v; }
        float sc = 1.0f / fmaxf(sqrtf(s), 1e-12f);
        #pragma unroll
        for (int e = 0; e < 16; ++e) dwv[t * 17 + e] *= sc;
    }
    __syncthreads();

    // ---- attention: thread = (row 0..63, e-group 0..3) ----
    const int row = t >> 2;        // 0..63 : (local head, d-channel)
    const int eg  = t & 3;         // which 4 of the 16 window positions
    const int lh  = row >> 5, dc = row & 31;
    const float tmpv = temp[h0 + lh];
    const float* qrow = &dwv[(lh * 32 + dc) * 17];

    float lg[32];
    float mx = -1e30f;
    #pragma unroll
    for (int f = 0; f < 32; ++f) {
        const float* krow = &dwv[(64 + lh * 32 + f) * 17];
        float s = 0.f;
        #pragma unroll
        for (int e = 0; e < 16; ++e) s += qrow[e] * krow[e];
        s *= tmpv;
        lg[f] = s;
        mx = fmaxf(mx, s);
    }
    float sum = 0.f;
    #pragma unroll
    for (int f = 0; f < 32; ++f) { lg[f] = __expf(lg[f] - mx); sum += lg[f]; }
    const float inv = 1.0f / sum;

    float o0 = 0, o1 = 0, o2 = 0, o3 = 0;
    #pragma unroll
    for (int f = 0; f < 32; ++f) {
        const float* vrow = &dwv[(128 + lh * 32 + f) * 17 + eg * 4];
        float p = lg[f] * inv;
        o0 += p * vrow[0]; o1 += p * vrow[1]; o2 += p * vrow[2]; o3 += p * vrow[3];
    }
    const int ch = (h0 + lh) * 32 + dc;
    const int gy = ih * 4 + eg;          // eg == ph for this thread's 4 e's
    *reinterpret_cast<float4*>(
        &attnout[(size_t)ch * NR + (gy - r0) * 128 + iw * 4]) =
        make_float4(o0, o1, o2, o3);
}

extern "C" void kernel_launch(void* const* d_in, const int* in_sizes, int n_in,
                              void* d_out, int out_size, void* d_ws, size_t ws_size,
                              hipStream_t stream) {
    const float* x     = (const float*)d_in[0];
    const float* Wqkv  = (const float*)d_in[1];
    const float* Wdw   = (const float*)d_in[2];
    const float* temp  = (const float*)d_in[3];
    const float* Wproj = (const float*)d_in[4];
    float* out = (float*)d_out;

    // pick row-strip height R (divisor of 128) so ws fits qkv + attn buffers
    int R = 128;
    const int divs[6] = {128, 64, 32, 16, 8, 4};
    for (int di = 0; di < 6; ++di) {
        R = divs[di];
        size_t qkvB = (size_t)768 * (size_t)(R + 2) * 128 * 4;
        size_t atB  = (size_t)256 * (size_t)R * 128 * 4;
        if (qkvB + atB <= ws_size) break;
    }
    size_t qkvBytes = (size_t)768 * (size_t)(R + 2) * 128 * 4;
    float* qkvbuf  = (float*)d_ws;
    float* attnbuf = (float*)((char*)d_ws + qkvBytes);

    for (int b = 0; b < 8; ++b) {
        for (int r0 = 0; r0 < 128; r0 += R) {
            const int r1  = r0 + R;
            const int r0h = (r0 > 0) ? r0 - 1 : 0;
            const int r1h = (r1 < 128) ? r1 + 1 : 128;
            const int Nh  = (r1h - r0h) * 128;
            const int NR  = R * 128;

            // K1: qkv = W_qkv @ x   (M=768, N=Nh)
            dim3 g1(Nh / 64, 768 / 64);
            gemm_f32_k256<<<g1, 256, 0, stream>>>(
                Wqkv, x + (size_t)b * CHW_ + (size_t)r0h * 128, qkvbuf,
                HW_, Nh);

            // K2: depthwise + windowed channel attention
            dim3 g2(32, R / 4, 4);
            attn_win<<<g2, 256, 0, stream>>>(
                qkvbuf, Wdw, temp, attnbuf, r0, r0h, Nh, NR);

            // K3: out = W_proj @ attn_out  (M=256, N=NR)
            dim3 g3(NR / 64, 256 / 64);
            gemm_f32_k256<<<g3, 256, 0, stream>>>(
                Wproj, attnbuf, out + (size_t)b * CHW_ + (size_t)r0 * 128,
                NR, HW_);
        }
    }
}

// Round 2
// 1601.956 us; speedup vs baseline: 1.3283x; 1.3283x over previous
//
#include <hip/hip_runtime.h>
#include <math.h>

// Channel attention (XCA-style), fp32. Round 2: split dwconv + windowed attn.
// b=8, c=256, H=W=128, heads=8, d=32, ps=4 -> nh=nw=32, e=16.
// Pipeline per batch/strip:
//   K1 qkv = W_qkv @ x            (GEMM M=768,K=256,N=pix)
//   K2 dwconv_win: depthwise 3x3 -> windowed layout dww[win][768][16]
//   K3 attn2: per-window l2norm + 32x32 channel attention + PV
//   K4 out = W_proj @ attn_out    (GEMM M=256,K=256,N=pix)

#define HW_ (128*128)
#define CHW_ (256*128*128)

// Generic fp32 GEMM, K fixed = 256. C[m,n] = sum_k A[m*256+k] * B[k*ldb+n].
__global__ __launch_bounds__(256) void gemm_f32_k256(
    const float* __restrict__ A,   // [M][256] row-major
    const float* __restrict__ Bp,  // (k,n) at Bp[k*ldb + n]
    float* __restrict__ Cp,        // (m,n) at Cp[m*ldc + n]
    int ldb, int ldc)
{
    __shared__ float As[64][17];   // [m][k], padded
    __shared__ float Bs[16][64];   // [k][n]
    const int t  = threadIdx.x;
    const int tx = t & 15;         // n/4
    const int ty = t >> 4;         // m/4
    const int m0 = blockIdx.y * 64;
    const int n0 = blockIdx.x * 64;

    float acc[4][4];
    #pragma unroll
    for (int i = 0; i < 4; ++i)
        #pragma unroll
        for (int j = 0; j < 4; ++j) acc[i][j] = 0.f;

    for (int k0 = 0; k0 < 256; k0 += 16) {
        #pragma unroll
        for (int i = 0; i < 4; ++i) {
            int idx = t + i * 256;
            int k = idx & 15, m = idx >> 4;
            As[m][k] = A[(m0 + m) * 256 + k0 + k];
        }
        {
            int k = t >> 4, n = (t & 15) * 4;
            const float4 v = *reinterpret_cast<const float4*>(
                Bp + (size_t)(k0 + k) * ldb + n0 + n);
            Bs[k][n + 0] = v.x; Bs[k][n + 1] = v.y;
            Bs[k][n + 2] = v.z; Bs[k][n + 3] = v.w;
        }
        __syncthreads();
        #pragma unroll
        for (int k = 0; k < 16; ++k) {
            float a0 = As[ty * 4 + 0][k];
            float a1 = As[ty * 4 + 1][k];
            float a2 = As[ty * 4 + 2][k];
            float a3 = As[ty * 4 + 3][k];
            float4 b = *reinterpret_cast<const float4*>(&Bs[k][tx * 4]);
            acc[0][0] += a0 * b.x; acc[0][1] += a0 * b.y; acc[0][2] += a0 * b.z; acc[0][3] += a0 * b.w;
            acc[1][0] += a1 * b.x; acc[1][1] += a1 * b.y; acc[1][2] += a1 * b.z; acc[1][3] += a1 * b.w;
            acc[2][0] += a2 * b.x; acc[2][1] += a2 * b.y; acc[2][2] += a2 * b.z; acc[2][3] += a2 * b.w;
            acc[3][0] += a3 * b.x; acc[3][1] += a3 * b.y; acc[3][2] += a3 * b.z; acc[3][3] += a3 * b.w;
        }
        __syncthreads();
    }
    #pragma unroll
    for (int i = 0; i < 4; ++i) {
        float4 v = make_float4(acc[i][0], acc[i][1], acc[i][2], acc[i][3]);
        *reinterpret_cast<float4*>(Cp + (size_t)(m0 + ty * 4 + i) * ldc + n0 + tx * 4) = v;
    }
}

// Depthwise 3x3 (SAME, zero pad) -> windowed layout.
// Block: 256 threads = 8 channels x 32 window-cols. Grid: (R/4, 96).
// Thread (chl, iw) computes one 4x4 window for channel ch, writes 16
// contiguous floats to dww[(wyl*32+iw)*768 + ch][16].
__global__ __launch_bounds__(256) void dwconv_win(
    const float* __restrict__ qkv,   // [768][Nh], rows [r0h, r1h)
    const float* __restrict__ Wdw,   // [768][9]
    float* __restrict__ dww,         // [nwin_strip][768][16]
    int r0, int r0h, int Nh)
{
    const int t   = threadIdx.x;
    const int iw  = t & 31;
    const int chl = t >> 5;
    const int wyl = blockIdx.x;
    const int ch  = blockIdx.y * 8 + chl;

    float w[9];
    #pragma unroll
    for (int i = 0; i < 9; ++i) w[i] = Wdw[ch * 9 + i];

    // register halo 6x6
    float h[6][6];
    const float* plane = qkv + (size_t)ch * Nh;
    #pragma unroll
    for (int r = 0; r < 6; ++r) {
        int gy = r0 + wyl * 4 - 1 + r;
        bool vy = (gy >= 0 && gy < 128);
        const float* rp = plane + (size_t)(gy - r0h) * 128;
        #pragma unroll
        for (int c = 0; c < 6; ++c) {
            int gx = iw * 4 - 1 + c;
            h[r][c] = (vy && gx >= 0 && gx < 128) ? rp[gx] : 0.f;
        }
    }

    float* outp = dww + ((size_t)(wyl * 32 + iw) * 768 + ch) * 16;
    #pragma unroll
    for (int py = 0; py < 4; ++py) {
        float4 o;
        float* op = &o.x;
        #pragma unroll
        for (int px = 0; px < 4; ++px) {
            float s = 0.f;
            #pragma unroll
            for (int dy = 0; dy < 3; ++dy)
                #pragma unroll
                for (int dx = 0; dx < 3; ++dx)
                    s += h[py + dy][px + dx] * w[dy * 3 + dx];
            op[px] = s;
        }
        *reinterpret_cast<float4*>(outp + py * 4) = o;
    }
}

// Per-window channel attention. Block = one window (all 8 heads).
// Grid: (32, R/4). LDS: s[768][17].
__global__ __launch_bounds__(256) void attn2(
    const float* __restrict__ dww,   // [nwin_strip][768][16]
    const float* __restrict__ temp,  // [8]
    float* __restrict__ attnout,     // [256][NR]
    int NR)
{
    __shared__ float s[768 * 17];
    const int t   = threadIdx.x;
    const int iw  = blockIdx.x;
    const int wyl = blockIdx.y;
    const int win = wyl * 32 + iw;

    // ---- load 768x16 contiguous ----
    const float* src = dww + (size_t)win * 12288;
    #pragma unroll
    for (int i = 0; i < 12; ++i) {
        int g4 = i * 256 + t;            // float4 index 0..3071
        int row = g4 >> 2, e4 = (g4 & 3) * 4;
        float4 v = *reinterpret_cast<const float4*>(src + g4 * 4);
        float* dp = &s[row * 17 + e4];
        dp[0] = v.x; dp[1] = v.y; dp[2] = v.z; dp[3] = v.w;
    }
    __syncthreads();

    // ---- l2norm q rows (0..255) and k rows (256..511) over e ----
    #pragma unroll
    for (int rr = 0; rr < 2; ++rr) {
        int r = t + rr * 256;
        float ss = 0.f;
        #pragma unroll
        for (int e = 0; e < 16; ++e) { float v = s[r * 17 + e]; ss += v * v; }
        float sc = 1.0f / fmaxf(sqrtf(ss), 1e-12f);
        #pragma unroll
        for (int e = 0; e < 16; ++e) s[r * 17 + e] *= sc;
    }
    __syncthreads();

    // ---- attention: thread = (head, d) ----
    const int head = t >> 5, d = t & 31;
    const float tmpv = temp[head];
    const float* qr = &s[(head * 32 + d) * 17];
    const float* kb = &s[(256 + head * 32) * 17];
    const float* vb = &s[(512 + head * 32) * 17];

    float lg[32];
    float mx = -1e30f;
    #pragma unroll
    for (int f = 0; f < 32; ++f) {
        const float* kr = kb + f * 17;
        float sv = 0.f;
        #pragma unroll
        for (int e = 0; e < 16; ++e) sv += qr[e] * kr[e];
        sv *= tmpv;
        lg[f] = sv;
        mx = fmaxf(mx, sv);
    }
    float sum = 0.f;
    #pragma unroll
    for (int f = 0; f < 32; ++f) { lg[f] = __expf(lg[f] - mx); sum += lg[f]; }
    const float inv = 1.0f / sum;

    float o[16];
    #pragma unroll
    for (int e = 0; e < 16; ++e) o[e] = 0.f;
    #pragma unroll
    for (int f = 0; f < 32; ++f) {
        float p = lg[f] * inv;
        const float* vr = vb + f * 17;
        #pragma unroll
        for (int e = 0; e < 16; ++e) o[e] += p * vr[e];
    }

    // ---- write: ch = t, 4 rows of float4 ----
    #pragma unroll
    for (int py = 0; py < 4; ++py) {
        float4 v = make_float4(o[py * 4 + 0], o[py * 4 + 1],
                               o[py * 4 + 2], o[py * 4 + 3]);
        *reinterpret_cast<float4*>(
            &attnout[(size_t)t * NR + (wyl * 4 + py) * 128 + iw * 4]) = v;
    }
}

extern "C" void kernel_launch(void* const* d_in, const int* in_sizes, int n_in,
                              void* d_out, int out_size, void* d_ws, size_t ws_size,
                              hipStream_t stream) {
    const float* x     = (const float*)d_in[0];
    const float* Wqkv  = (const float*)d_in[1];
    const float* Wdw   = (const float*)d_in[2];
    const float* temp  = (const float*)d_in[3];
    const float* Wproj = (const float*)d_in[4];
    float* out = (float*)d_out;

    // strip height R (divisor of 128) so ws fits qkv + dww + attn buffers
    int R = 128;
    const int divs[6] = {128, 64, 32, 16, 8, 4};
    for (int di = 0; di < 6; ++di) {
        R = divs[di];
        size_t qkvB = (size_t)768 * (size_t)(R + 2) * 128 * 4;
        size_t dwwB = (size_t)768 * (size_t)R * 128 * 4;
        size_t atB  = (size_t)256 * (size_t)R * 128 * 4;
        if (qkvB + dwwB + atB <= ws_size) break;
    }
    size_t qkvBytes = (size_t)768 * (size_t)(R + 2) * 128 * 4;
    size_t dwwBytes = (size_t)768 * (size_t)R * 128 * 4;
    float* qkvbuf  = (float*)d_ws;
    float* dwwbuf  = (float*)((char*)d_ws + qkvBytes);
    float* attnbuf = (float*)((char*)d_ws + qkvBytes + dwwBytes);

    for (int b = 0; b < 8; ++b) {
        for (int r0 = 0; r0 < 128; r0 += R) {
            const int r1  = r0 + R;
            const int r0h = (r0 > 0) ? r0 - 1 : 0;
            const int r1h = (r1 < 128) ? r1 + 1 : 128;
            const int Nh  = (r1h - r0h) * 128;
            const int NR  = R * 128;

            // K1: qkv = W_qkv @ x
            dim3 g1(Nh / 64, 768 / 64);
            gemm_f32_k256<<<g1, 256, 0, stream>>>(
                Wqkv, x + (size_t)b * CHW_ + (size_t)r0h * 128, qkvbuf,
                HW_, Nh);

            // K2: depthwise 3x3 -> windowed
            dim3 g2(R / 4, 96);
            dwconv_win<<<g2, 256, 0, stream>>>(
                qkvbuf, Wdw, dwwbuf, r0, r0h, Nh);

            // K3: per-window channel attention
            dim3 g3(32, R / 4);
            attn2<<<g3, 256, 0, stream>>>(
                dwwbuf, temp, attnbuf, NR);

            // K4: out = W_proj @ attn_out
            dim3 g4(NR / 64, 256 / 64);
            gemm_f32_k256<<<g4, 256, 0, stream>>>(
                Wproj, attnbuf, out + (size_t)b * CHW_ + (size_t)r0 * 128,
                NR, HW_);
        }
    }
}

// Round 3
// 745.282 us; speedup vs baseline: 2.8551x; 2.1495x over previous
//
#include <hip/hip_runtime.h>
#include <math.h>

// Channel attention (XCA-style). Round 3: bf16 MFMA GEMMs.
// b=8, c=256, H=W=128, heads=8, d=32, ps=4 -> nh=nw=32, e=16.
// Pipeline per batch/strip:
//   conv_w  : W_qkv, W_proj -> bf16 (once)
//   conv_xt : x strip fp32 [c][p] -> xT bf16 [p][c]
//   K1 gemm_bf16: qkv = Wqkv_b @ xT^T   (M=768,K=256,N=pix) -> fp32 [o][p]
//   K2 dwconv_win: depthwise 3x3 -> windowed layout dww[win][768][16]
//   K3 attn2: per-window l2norm + 32x32 channel attention + PV -> attnT bf16 [p][c]
//   K4 gemm_bf16: out = Wproj_b @ attnT^T -> fp32 [o][p]

#define HW_ (128*128)
#define CHW_ (256*128*128)

typedef __attribute__((ext_vector_type(8))) short short8;
typedef __attribute__((ext_vector_type(4))) float f32x4;

static __device__ __forceinline__ unsigned short f2bf(float f) {
    unsigned int u = __float_as_uint(f);
    unsigned int r = (u + 0x7fffu + ((u >> 16) & 1u)) >> 16;   // RNE
    return (unsigned short)r;
}

// ---- weights fp32 -> bf16 (768*256 + 256*256 = 262144 elems) ----
__global__ __launch_bounds__(256) void conv_w(
    const float* __restrict__ Wq, const float* __restrict__ Wp,
    unsigned short* __restrict__ out)
{
    int i = blockIdx.x * 256 + threadIdx.x;
    float v = (i < 196608) ? Wq[i] : Wp[i - 196608];
    out[i] = f2bf(v);
}

// ---- x strip [256][Nh] fp32 (row stride ldx) -> xT [Nh][256] bf16 ----
__global__ __launch_bounds__(256) void conv_xt(
    const float* __restrict__ xs, unsigned short* __restrict__ xT, int ldx)
{
    __shared__ float tile[64][65];
    const int t = threadIdx.x;
    const int p0 = blockIdx.x * 64, c0 = blockIdx.y * 64;
    {
        const int cl = t >> 4, pl = (t & 15) * 4;
        #pragma unroll
        for (int i = 0; i < 4; ++i) {
            float4 v = *reinterpret_cast<const float4*>(
                xs + (size_t)(c0 + cl + i * 16) * ldx + p0 + pl);
            tile[cl + i * 16][pl + 0] = v.x;
            tile[cl + i * 16][pl + 1] = v.y;
            tile[cl + i * 16][pl + 2] = v.z;
            tile[cl + i * 16][pl + 3] = v.w;
        }
    }
    __syncthreads();
    #pragma unroll
    for (int i = 0; i < 2; ++i) {
        int chunk = i * 256 + t;
        int pr = chunk >> 3, c8 = (chunk & 7) * 8;
        short8 o;
        #pragma unroll
        for (int j = 0; j < 8; ++j)
            o[j] = (short)f2bf(tile[c8 + j][pr]);
        *reinterpret_cast<short8*>(xT + (size_t)(p0 + pr) * 256 + c0 + c8) = o;
    }
}

// ---- bf16 MFMA GEMM: C[m][n] = sum_k A[m][k] * Bt[n][k], K=256 ----
// 128x128 tile, 4 waves (2x2), each 64x64 via 4x4 frags of 16x16x32.
// LDS chunk swizzle (both sides): pos = r*4 + (c ^ ((r ^ r>>2) & 3)).
__global__ __launch_bounds__(256) void gemm_bf16(
    const unsigned short* __restrict__ A,   // [M][256] bf16
    const unsigned short* __restrict__ Bt,  // [N][256] bf16
    float* __restrict__ C, int ldc)
{
    __shared__ __align__(16) unsigned short Asm[128 * 32];
    __shared__ __align__(16) unsigned short Bsm[128 * 32];
    const int t = threadIdx.x;
    const int lane = t & 63, wid = t >> 6;
    const int m0 = blockIdx.y * 128, n0 = blockIdx.x * 128;
    const int wr = wid >> 1, wc = wid & 1;
    const int l15 = lane & 15, l4 = lane >> 4;

    // staging sources: chunk u = i*256 + t holds logical (r=u>>2, c=cs^g(r))
    const unsigned short* srcA[2];
    const unsigned short* srcB[2];
    #pragma unroll
    for (int i = 0; i < 2; ++i) {
        int u = i * 256 + t;
        int r = u >> 2, cs = u & 3;
        int c = cs ^ ((r ^ (r >> 2)) & 3);
        srcA[i] = A  + (size_t)(m0 + r) * 256 + c * 8;
        srcB[i] = Bt + (size_t)(n0 + r) * 256 + c * 8;
    }

    // fragment read chunk indices (swizzled), loop-invariant
    int ar[4], br[4];
    #pragma unroll
    for (int i = 0; i < 4; ++i) {
        int rm = wr * 64 + i * 16 + l15;
        ar[i] = rm * 4 + (l4 ^ ((rm ^ (rm >> 2)) & 3));
        int rn = wc * 64 + i * 16 + l15;
        br[i] = rn * 4 + (l4 ^ ((rn ^ (rn >> 2)) & 3));
    }

    f32x4 acc[4][4];
    #pragma unroll
    for (int i = 0; i < 4; ++i)
        #pragma unroll
        for (int j = 0; j < 4; ++j)
            acc[i][j] = (f32x4){0.f, 0.f, 0.f, 0.f};

    const short8* Ab = (const short8*)Asm;
    const short8* Bb = (const short8*)Bsm;
    char* ldsA = (char*)Asm;
    char* ldsB = (char*)Bsm;

    for (int k0 = 0; k0 < 256; k0 += 32) {
        __syncthreads();
        #pragma unroll
        for (int i = 0; i < 2; ++i) {
            __builtin_amdgcn_global_load_lds(
                (const __attribute__((address_space(1))) void*)(srcA[i] + k0),
                (__attribute__((address_space(3))) void*)(ldsA + i * 4096 + wid * 1024),
                16, 0, 0);
            __builtin_amdgcn_global_load_lds(
                (const __attribute__((address_space(1))) void*)(srcB[i] + k0),
                (__attribute__((address_space(3))) void*)(ldsB + i * 4096 + wid * 1024),
                16, 0, 0);
        }
        __syncthreads();
        short8 af[4], bf[4];
        #pragma unroll
        for (int i = 0; i < 4; ++i) { af[i] = Ab[ar[i]]; bf[i] = Bb[br[i]]; }
        #pragma unroll
        for (int am = 0; am < 4; ++am)
            #pragma unroll
            for (int bn = 0; bn < 4; ++bn)
                acc[am][bn] = __builtin_amdgcn_mfma_f32_16x16x32_bf16(
                    af[am], bf[bn], acc[am][bn], 0, 0, 0);
    }

    // C/D layout: col = lane&15, row = (lane>>4)*4 + reg
    #pragma unroll
    for (int am = 0; am < 4; ++am)
        #pragma unroll
        for (int q = 0; q < 4; ++q) {
            int m = m0 + wr * 64 + am * 16 + l4 * 4 + q;
            #pragma unroll
            for (int bn = 0; bn < 4; ++bn) {
                int n = n0 + wc * 64 + bn * 16 + l15;
                C[(size_t)m * ldc + n] = acc[am][bn][q];
            }
        }
}

// ---- depthwise 3x3 (SAME, zero pad) -> windowed layout ----
__global__ __launch_bounds__(256) void dwconv_win(
    const float* __restrict__ qkv,   // [768][Nh], rows [r0h, r1h)
    const float* __restrict__ Wdw,   // [768][9]
    float* __restrict__ dww,         // [nwin_strip][768][16]
    int r0, int r0h, int Nh)
{
    const int t   = threadIdx.x;
    const int iw  = t & 31;
    const int chl = t >> 5;
    const int wyl = blockIdx.x;
    const int ch  = blockIdx.y * 8 + chl;

    float w[9];
    #pragma unroll
    for (int i = 0; i < 9; ++i) w[i] = Wdw[ch * 9 + i];

    float h[6][6];
    const float* plane = qkv + (size_t)ch * Nh;
    #pragma unroll
    for (int r = 0; r < 6; ++r) {
        int gy = r0 + wyl * 4 - 1 + r;
        bool vy = (gy >= 0 && gy < 128);
        const float* rp = plane + (size_t)(gy - r0h) * 128;
        #pragma unroll
        for (int c = 0; c < 6; ++c) {
            int gx = iw * 4 - 1 + c;
            h[r][c] = (vy && gx >= 0 && gx < 128) ? rp[gx] : 0.f;
        }
    }

    float* outp = dww + ((size_t)(wyl * 32 + iw) * 768 + ch) * 16;
    #pragma unroll
    for (int py = 0; py < 4; ++py) {
        float4 o;
        float* op = &o.x;
        #pragma unroll
        for (int px = 0; px < 4; ++px) {
            float s = 0.f;
            #pragma unroll
            for (int dy = 0; dy < 3; ++dy)
                #pragma unroll
                for (int dx = 0; dx < 3; ++dx)
                    s += h[py + dy][px + dx] * w[dy * 3 + dx];
            op[px] = s;
        }
        *reinterpret_cast<float4*>(outp + py * 4) = o;
    }
}

// ---- per-window channel attention; writes attnT bf16 [p_local][256] ----
__global__ __launch_bounds__(256) void attn2(
    const float* __restrict__ dww,   // [nwin_strip][768][16]
    const float* __restrict__ temp,  // [8]
    unsigned short* __restrict__ attnT)
{
    __shared__ float s[768 * 17];
    const int t   = threadIdx.x;
    const int iw  = blockIdx.x;
    const int wyl = blockIdx.y;
    const int win = wyl * 32 + iw;

    const float* src = dww + (size_t)win * 12288;
    #pragma unroll
    for (int i = 0; i < 12; ++i) {
        int g4 = i * 256 + t;
        int row = g4 >> 2, e4 = (g4 & 3) * 4;
        float4 v = *reinterpret_cast<const float4*>(src + g4 * 4);
        float* dp = &s[row * 17 + e4];
        dp[0] = v.x; dp[1] = v.y; dp[2] = v.z; dp[3] = v.w;
    }
    __syncthreads();

    #pragma unroll
    for (int rr = 0; rr < 2; ++rr) {
        int r = t + rr * 256;
        float ss = 0.f;
        #pragma unroll
        for (int e = 0; e < 16; ++e) { float v = s[r * 17 + e]; ss += v * v; }
        float sc = 1.0f / fmaxf(sqrtf(ss), 1e-12f);
        #pragma unroll
        for (int e = 0; e < 16; ++e) s[r * 17 + e] *= sc;
    }
    __syncthreads();

    const int head = t >> 5, d = t & 31;
    const float tmpv = temp[head];
    const float* qr = &s[(head * 32 + d) * 17];
    const float* kb = &s[(256 + head * 32) * 17];
    const float* vb = &s[(512 + head * 32) * 17];

    float lg[32];
    float mx = -1e30f;
    #pragma unroll
    for (int f = 0; f < 32; ++f) {
        const float* kr = kb + f * 17;
        float sv = 0.f;
        #pragma unroll
        for (int e = 0; e < 16; ++e) sv += qr[e] * kr[e];
        sv *= tmpv;
        lg[f] = sv;
        mx = fmaxf(mx, sv);
    }
    float sum = 0.f;
    #pragma unroll
    for (int f = 0; f < 32; ++f) { lg[f] = __expf(lg[f] - mx); sum += lg[f]; }
    const float inv = 1.0f / sum;

    float o[16];
    #pragma unroll
    for (int e = 0; e < 16; ++e) o[e] = 0.f;
    #pragma unroll
    for (int f = 0; f < 32; ++f) {
        float p = lg[f] * inv;
        const float* vr = vb + f * 17;
        #pragma unroll
        for (int e = 0; e < 16; ++e) o[e] += p * vr[e];
    }

    // write transposed bf16: attnT[p_local][ch], ch = t (coalesced over t)
    #pragma unroll
    for (int e = 0; e < 16; ++e) {
        int py = e >> 2, px = e & 3;
        int pl = (wyl * 4 + py) * 128 + iw * 4 + px;
        attnT[(size_t)pl * 256 + t] = f2bf(o[e]);
    }
}

extern "C" void kernel_launch(void* const* d_in, const int* in_sizes, int n_in,
                              void* d_out, int out_size, void* d_ws, size_t ws_size,
                              hipStream_t stream) {
    const float* x     = (const float*)d_in[0];
    const float* Wqkv  = (const float*)d_in[1];
    const float* Wdw   = (const float*)d_in[2];
    const float* temp  = (const float*)d_in[3];
    const float* Wproj = (const float*)d_in[4];
    float* out = (float*)d_out;

    unsigned short* Wb = (unsigned short*)d_ws;        // 262144 bf16
    const size_t offW = 262144 * 2;

    // pick strip height R (divisor of 128) so ws fits all buffers
    int R = 128;
    const int divs[6] = {128, 64, 32, 16, 8, 4};
    size_t xtB = 0, qkvB = 0, dwwB = 0;
    for (int di = 0; di < 6; ++di) {
        R = divs[di];
        int NhMax = ((R == 128) ? 128 : (R + 2)) * 128;
        xtB  = (size_t)NhMax * 256 * 2;
        qkvB = (size_t)768 * NhMax * 4;
        dwwB = (size_t)768 * R * 128 * 4;
        size_t atB = (size_t)R * 128 * 256 * 2;
        if (offW + xtB + qkvB + dwwB + atB <= ws_size) break;
    }
    unsigned short* xT      = (unsigned short*)((char*)d_ws + offW);
    float*          qkvbuf  = (float*)((char*)d_ws + offW + xtB);
    float*          dwwbuf  = (float*)((char*)d_ws + offW + xtB + qkvB);
    unsigned short* attnT   = (unsigned short*)((char*)d_ws + offW + xtB + qkvB + dwwB);

    conv_w<<<1024, 256, 0, stream>>>(Wqkv, Wproj, Wb);

    for (int b = 0; b < 8; ++b) {
        for (int r0 = 0; r0 < 128; r0 += R) {
            const int r1  = r0 + R;
            const int r0h = (r0 > 0) ? r0 - 1 : 0;
            const int r1h = (r1 < 128) ? r1 + 1 : 128;
            const int Nh  = (r1h - r0h) * 128;
            const int NR  = R * 128;

            // x strip -> xT bf16 [Nh][256]
            conv_xt<<<dim3(Nh / 64, 4), 256, 0, stream>>>(
                x + (size_t)b * CHW_ + (size_t)r0h * 128, xT, HW_);

            // K1: qkv = Wqkv_b @ xT^T
            gemm_bf16<<<dim3(Nh / 128, 6), 256, 0, stream>>>(
                Wb, xT, qkvbuf, Nh);

            // K2: depthwise 3x3 -> windowed
            dwconv_win<<<dim3(R / 4, 96), 256, 0, stream>>>(
                qkvbuf, Wdw, dwwbuf, r0, r0h, Nh);

            // K3: per-window channel attention -> attnT bf16 [NR][256]
            attn2<<<dim3(32, R / 4), 256, 0, stream>>>(
                dwwbuf, temp, attnT);

            // K4: out = Wproj_b @ attnT^T
            gemm_bf16<<<dim3(NR / 128, 2), 256, 0, stream>>>(
                Wb + 196608, attnT, out + (size_t)b * CHW_ + (size_t)r0 * 128,
                HW_);
        }
    }
}

// Round 4
// 536.811 us; speedup vs baseline: 3.9638x; 1.3884x over previous
//
#include <hip/hip_runtime.h>
#include <math.h>

// Channel attention (XCA-style). Round 4: bf16 intermediates + batch grouping.
// b=8, c=256, H=W=128, heads=8, d=32, ps=4 -> nh=nw=32, e=16.
// Per group of G batches:
//   conv_xt : x fp32 [b][c][p] -> xT bf16 [b*p][256]
//   K1 gemm<bf16out>: qkv = Wqkv_b @ xT^T -> bf16 [b][768][16384]
//   K2 dwconv_win: depthwise 3x3 -> bf16 dww[b][win][768][16]
//   K3 attn2: l2norm + 32x32 channel attn + PV -> attnT bf16 [b*p][256]
//   K4 gemm<f32out>: out = Wproj_b @ attnT^T -> fp32 [b][256][16384]

#define HW_ (128*128)
#define CHW_ (256*128*128)

typedef __attribute__((ext_vector_type(8))) short short8;
typedef __attribute__((ext_vector_type(4))) float f32x4;

static __device__ __forceinline__ unsigned short f2bf(float f) {
    unsigned int u = __float_as_uint(f);
    unsigned int r = (u + 0x7fffu + ((u >> 16) & 1u)) >> 16;   // RNE
    return (unsigned short)r;
}
static __device__ __forceinline__ float bf2f(unsigned short u) {
    return __uint_as_float(((unsigned int)u) << 16);
}

// ---- weights fp32 -> bf16 (768*256 + 256*256 = 262144 elems) ----
__global__ __launch_bounds__(256) void conv_w(
    const float* __restrict__ Wq, const float* __restrict__ Wp,
    unsigned short* __restrict__ out)
{
    int i = blockIdx.x * 256 + threadIdx.x;
    float v = (i < 196608) ? Wq[i] : Wp[i - 196608];
    out[i] = f2bf(v);
}

// ---- x [b][256][16384] fp32 -> xT [b*16384][256] bf16 ----
__global__ __launch_bounds__(256) void conv_xt(
    const float* __restrict__ xs, unsigned short* __restrict__ xT)
{
    __shared__ float tile[64][65];
    const int t = threadIdx.x;
    const int p0 = blockIdx.x * 64, c0 = blockIdx.y * 64;
    const float* xb = xs + (size_t)blockIdx.z * CHW_;
    unsigned short* xTb = xT + (size_t)blockIdx.z * HW_ * 256;
    {
        const int cl = t >> 4, pl = (t & 15) * 4;
        #pragma unroll
        for (int i = 0; i < 4; ++i) {
            float4 v = *reinterpret_cast<const float4*>(
                xb + (size_t)(c0 + cl + i * 16) * HW_ + p0 + pl);
            tile[cl + i * 16][pl + 0] = v.x;
            tile[cl + i * 16][pl + 1] = v.y;
            tile[cl + i * 16][pl + 2] = v.z;
            tile[cl + i * 16][pl + 3] = v.w;
        }
    }
    __syncthreads();
    #pragma unroll
    for (int i = 0; i < 2; ++i) {
        int chunk = i * 256 + t;
        int pr = chunk >> 3, c8 = (chunk & 7) * 8;
        short8 o;
        #pragma unroll
        for (int j = 0; j < 8; ++j)
            o[j] = (short)f2bf(tile[c8 + j][pr]);
        *reinterpret_cast<short8*>(xTb + (size_t)(p0 + pr) * 256 + c0 + c8) = o;
    }
}

// ---- bf16 MFMA GEMM: C[b][m][n] = sum_k A[m][k] * Bt[b*16384+n][k], K=256 --
// 128x128 tile, 4 waves (2x2), 4x4 frags of 16x16x32, fp32 accum.
// BF16OUT=1: LDS-transpose epilogue, bf16 coalesced stores.
template<int BF16OUT>
__global__ __launch_bounds__(256) void gemm_bf16(
    const unsigned short* __restrict__ A,   // [M][256] bf16
    const unsigned short* __restrict__ Bt,  // [N][256] bf16
    void* __restrict__ Cv,                  // [G][M][16384]
    size_t strideBatch)                     // = M*16384
{
    __shared__ __align__(16) char smem[BF16OUT ? 16896 : 16384];
    unsigned short* Asm = (unsigned short*)smem;
    unsigned short* Bsm = (unsigned short*)(smem + 8192);

    const int t = threadIdx.x;
    const int lane = t & 63, wid = t >> 6;
    const int m0 = blockIdx.y * 128, n0 = blockIdx.x * 128;
    const int nb = n0 >> 14, nloc0 = n0 & 16383;
    const int wr = wid >> 1, wc = wid & 1;
    const int l15 = lane & 15, l4 = lane >> 4;

    // staging sources: chunk u = i*256 + t holds logical (r=u>>2, c=cs^g(r))
    const unsigned short* srcA[2];
    const unsigned short* srcB[2];
    #pragma unroll
    for (int i = 0; i < 2; ++i) {
        int u = i * 256 + t;
        int r = u >> 2, cs = u & 3;
        int c = cs ^ ((r ^ (r >> 2)) & 3);
        srcA[i] = A  + (size_t)(m0 + r) * 256 + c * 8;
        srcB[i] = Bt + (size_t)(n0 + r) * 256 + c * 8;
    }

    // fragment read chunk indices (swizzled), loop-invariant
    int ar[4], br[4];
    #pragma unroll
    for (int i = 0; i < 4; ++i) {
        int rm = wr * 64 + i * 16 + l15;
        ar[i] = rm * 4 + (l4 ^ ((rm ^ (rm >> 2)) & 3));
        int rn = wc * 64 + i * 16 + l15;
        br[i] = rn * 4 + (l4 ^ ((rn ^ (rn >> 2)) & 3));
    }

    f32x4 acc[4][4];
    #pragma unroll
    for (int i = 0; i < 4; ++i)
        #pragma unroll
        for (int j = 0; j < 4; ++j)
            acc[i][j] = (f32x4){0.f, 0.f, 0.f, 0.f};

    const short8* Ab = (const short8*)Asm;
    const short8* Bb = (const short8*)Bsm;

    for (int k0 = 0; k0 < 256; k0 += 32) {
        __syncthreads();
        #pragma unroll
        for (int i = 0; i < 2; ++i) {
            __builtin_amdgcn_global_load_lds(
                (const __attribute__((address_space(1))) void*)(srcA[i] + k0),
                (__attribute__((address_space(3))) void*)(smem + i * 4096 + wid * 1024),
                16, 0, 0);
            __builtin_amdgcn_global_load_lds(
                (const __attribute__((address_space(1))) void*)(srcB[i] + k0),
                (__attribute__((address_space(3))) void*)(smem + 8192 + i * 4096 + wid * 1024),
                16, 0, 0);
        }
        __syncthreads();
        short8 af[4], bf[4];
        #pragma unroll
        for (int i = 0; i < 4; ++i) { af[i] = Ab[ar[i]]; bf[i] = Bb[br[i]]; }
        #pragma unroll
        for (int am = 0; am < 4; ++am)
            #pragma unroll
            for (int bn = 0; bn < 4; ++bn)
                acc[am][bn] = __builtin_amdgcn_mfma_f32_16x16x32_bf16(
                    af[am], bf[bn], acc[am][bn], 0, 0, 0);
    }

    // C/D frag layout: col = lane&15, row = (lane>>4)*4 + reg
    if (BF16OUT) {
        unsigned short* Co = (unsigned short*)Cv + (size_t)nb * strideBatch + nloc0;
        float* ep = (float*)smem;          // [32][132]
        const int rr = t >> 3, c0 = (t & 7) * 16;
        #pragma unroll
        for (int am = 0; am < 4; ++am) {
            __syncthreads();
            #pragma unroll
            for (int q = 0; q < 4; ++q)
                #pragma unroll
                for (int bn = 0; bn < 4; ++bn)
                    ep[(wr * 16 + l4 * 4 + q) * 132 + wc * 64 + bn * 16 + l15] =
                        acc[am][bn][q];
            __syncthreads();
            short8 o0, o1;
            #pragma unroll
            for (int j = 0; j < 8; ++j) {
                o0[j] = (short)f2bf(ep[rr * 132 + c0 + j]);
                o1[j] = (short)f2bf(ep[rr * 132 + c0 + 8 + j]);
            }
            int m = m0 + (rr >> 4) * 64 + am * 16 + (rr & 15);
            unsigned short* p = Co + (size_t)m * 16384 + c0;
            *reinterpret_cast<short8*>(p) = o0;
            *reinterpret_cast<short8*>(p + 8) = o1;
        }
    } else {
        float* Co = (float*)Cv + (size_t)nb * strideBatch + nloc0;
        #pragma unroll
        for (int am = 0; am < 4; ++am)
            #pragma unroll
            for (int q = 0; q < 4; ++q) {
                int m = m0 + wr * 64 + am * 16 + l4 * 4 + q;
                #pragma unroll
                for (int bn = 0; bn < 4; ++bn)
                    Co[(size_t)m * 16384 + wc * 64 + bn * 16 + l15] =
                        acc[am][bn][q];
            }
    }
}

// ---- depthwise 3x3 (SAME, zero pad), bf16 in -> bf16 windowed out ----
__global__ __launch_bounds__(256) void dwconv_win(
    const unsigned short* __restrict__ qkv,  // [G][768][16384] bf16
    const float* __restrict__ Wdw,           // [768][9]
    unsigned short* __restrict__ dww)        // [G][1024][768][16] bf16
{
    const int t   = threadIdx.x;
    const int iw  = t & 31;
    const int chl = t >> 5;
    const int wyl = blockIdx.x;
    const int ch  = blockIdx.y * 8 + chl;
    const int bz  = blockIdx.z;

    float w[9];
    #pragma unroll
    for (int i = 0; i < 9; ++i) w[i] = Wdw[ch * 9 + i];

    float h[6][6];
    const unsigned short* plane = qkv + (size_t)(bz * 768 + ch) * HW_;
    #pragma unroll
    for (int r = 0; r < 6; ++r) {
        int gy = wyl * 4 - 1 + r;
        bool vy = (gy >= 0 && gy < 128);
        const unsigned short* rp = plane + (size_t)gy * 128;
        #pragma unroll
        for (int c = 0; c < 6; ++c) {
            int gx = iw * 4 - 1 + c;
            h[r][c] = (vy && gx >= 0 && gx < 128) ? bf2f(rp[gx]) : 0.f;
        }
    }

    unsigned short* outp =
        dww + ((size_t)(bz * 1024 + wyl * 32 + iw) * 768 + ch) * 16;
    short8 o0, o1;
    #pragma unroll
    for (int py = 0; py < 4; ++py) {
        #pragma unroll
        for (int px = 0; px < 4; ++px) {
            float s = 0.f;
            #pragma unroll
            for (int dy = 0; dy < 3; ++dy)
                #pragma unroll
                for (int dx = 0; dx < 3; ++dx)
                    s += h[py + dy][px + dx] * w[dy * 3 + dx];
            int e = py * 4 + px;
            if (e < 8) o0[e] = (short)f2bf(s); else o1[e - 8] = (short)f2bf(s);
        }
    }
    *reinterpret_cast<short8*>(outp) = o0;
    *reinterpret_cast<short8*>(outp + 8) = o1;
}

// ---- per-window channel attention; writes attnT bf16 [b*p][256] ----
__global__ __launch_bounds__(256) void attn2(
    const unsigned short* __restrict__ dww,  // [G][1024][768][16] bf16
    const float* __restrict__ temp,          // [8]
    unsigned short* __restrict__ attnT)      // [G*16384][256]
{
    __shared__ float s[768 * 17];
    const int t   = threadIdx.x;
    const int iw  = blockIdx.x;
    const int wyl = blockIdx.y;
    const int bz  = blockIdx.z;
    const int win = bz * 1024 + wyl * 32 + iw;

    const unsigned short* src = dww + (size_t)win * 12288;
    #pragma unroll
    for (int i = 0; i < 6; ++i) {
        int g = i * 256 + t;                 // short8 chunk 0..1535
        short8 v = reinterpret_cast<const short8*>(src)[g];
        int row = g >> 1, e8 = (g & 1) * 8;
        float* dp = &s[row * 17 + e8];
        #pragma unroll
        for (int j = 0; j < 8; ++j) dp[j] = bf2f((unsigned short)v[j]);
    }
    __syncthreads();

    #pragma unroll
    for (int rr = 0; rr < 2; ++rr) {
        int r = t + rr * 256;
        float ss = 0.f;
        #pragma unroll
        for (int e = 0; e < 16; ++e) { float v = s[r * 17 + e]; ss += v * v; }
        float sc = 1.0f / fmaxf(sqrtf(ss), 1e-12f);
        #pragma unroll
        for (int e = 0; e < 16; ++e) s[r * 17 + e] *= sc;
    }
    __syncthreads();

    const int head = t >> 5, d = t & 31;
    const float tmpv = temp[head];
    const float* qr = &s[(head * 32 + d) * 17];
    const float* kb = &s[(256 + head * 32) * 17];
    const float* vb = &s[(512 + head * 32) * 17];

    float lg[32];
    float mx = -1e30f;
    #pragma unroll
    for (int f = 0; f < 32; ++f) {
        const float* kr = kb + f * 17;
        float sv = 0.f;
        #pragma unroll
        for (int e = 0; e < 16; ++e) sv += qr[e] * kr[e];
        sv *= tmpv;
        lg[f] = sv;
        mx = fmaxf(mx, sv);
    }
    float sum = 0.f;
    #pragma unroll
    for (int f = 0; f < 32; ++f) { lg[f] = __expf(lg[f] - mx); sum += lg[f]; }
    const float inv = 1.0f / sum;

    float o[16];
    #pragma unroll
    for (int e = 0; e < 16; ++e) o[e] = 0.f;
    #pragma unroll
    for (int f = 0; f < 32; ++f) {
        float p = lg[f] * inv;
        const float* vr = vb + f * 17;
        #pragma unroll
        for (int e = 0; e < 16; ++e) o[e] += p * vr[e];
    }

    #pragma unroll
    for (int e = 0; e < 16; ++e) {
        int py = e >> 2, px = e & 3;
        size_t pl = (size_t)bz * HW_ + (wyl * 4 + py) * 128 + iw * 4 + px;
        attnT[pl * 256 + t] = f2bf(o[e]);
    }
}

extern "C" void kernel_launch(void* const* d_in, const int* in_sizes, int n_in,
                              void* d_out, int out_size, void* d_ws, size_t ws_size,
                              hipStream_t stream) {
    const float* x     = (const float*)d_in[0];
    const float* Wqkv  = (const float*)d_in[1];
    const float* Wdw   = (const float*)d_in[2];
    const float* temp  = (const float*)d_in[3];
    const float* Wproj = (const float*)d_in[4];
    float* out = (float*)d_out;

    unsigned short* Wb = (unsigned short*)d_ws;        // 262144 bf16
    const size_t offW = 262144 * 2;

    // per-batch buffer bytes
    const size_t xtB  = (size_t)HW_ * 256 * 2;         // 8 MiB
    const size_t qkvB = (size_t)768 * HW_ * 2;         // 24 MiB
    const size_t dwwB = (size_t)1024 * 768 * 16 * 2;   // 24 MiB
    const size_t atB  = (size_t)HW_ * 256 * 2;         // 8 MiB
    const size_t perB = xtB + qkvB + dwwB + atB;       // 64 MiB

    int G = 8;
    while (G > 1 && offW + (size_t)G * perB > ws_size) G >>= 1;

    unsigned short* xT    = (unsigned short*)((char*)d_ws + offW);
    unsigned short* qkv   = (unsigned short*)((char*)d_ws + offW + (size_t)G * xtB);
    unsigned short* dww   = (unsigned short*)((char*)d_ws + offW + (size_t)G * (xtB + qkvB));
    unsigned short* attnT = (unsigned short*)((char*)d_ws + offW + (size_t)G * (xtB + qkvB + dwwB));

    conv_w<<<1024, 256, 0, stream>>>(Wqkv, Wproj, Wb);

    for (int b0 = 0; b0 < 8; b0 += G) {
        conv_xt<<<dim3(HW_ / 64, 4, G), 256, 0, stream>>>(
            x + (size_t)b0 * CHW_, xT);

        gemm_bf16<1><<<dim3(G * 128, 6), 256, 0, stream>>>(
            Wb, xT, qkv, (size_t)768 * HW_);

        dwconv_win<<<dim3(32, 96, G), 256, 0, stream>>>(
            qkv, Wdw, dww);

        attn2<<<dim3(32, 32, G), 256, 0, stream>>>(
            dww, temp, attnT);

        gemm_bf16<0><<<dim3(G * 128, 2), 256, 0, stream>>>(
            Wb + 196608, attnT, out + (size_t)b0 * CHW_, (size_t)CHW_);
    }
}

// Round 5
// 481.849 us; speedup vs baseline: 4.4160x; 1.1141x over previous
//
#include <hip/hip_runtime.h>
#include <math.h>

// Channel attention (XCA-style). Round 5: LDS-vectorized attn2.
// b=8, c=256, H=W=128, heads=8, d=32, ps=4 -> nh=nw=32, e=16.
// Per group of G batches:
//   conv_xt : x fp32 [b][c][p] -> xT bf16 [b*p][256]
//   K1 gemm<bf16out>: qkv = Wqkv_b @ xT^T -> bf16 [b][768][16384]
//   K2 dwconv_win: depthwise 3x3 -> bf16 dww[b][win][768][16]
//   K3 attn2: l2norm + 32x32 channel attn + PV -> attnT bf16 [b*p][256]
//       (q in regs; k,v in LDS rows padded to 20 floats -> all b128 ops)
//   K4 gemm<f32out>: out = Wproj_b @ attnT^T -> fp32 [b][256][16384]

#define HW_ (128*128)
#define CHW_ (256*128*128)

typedef __attribute__((ext_vector_type(8))) short short8;
typedef __attribute__((ext_vector_type(4))) float f32x4;

static __device__ __forceinline__ unsigned short f2bf(float f) {
    unsigned int u = __float_as_uint(f);
    unsigned int r = (u + 0x7fffu + ((u >> 16) & 1u)) >> 16;   // RNE
    return (unsigned short)r;
}
static __device__ __forceinline__ float bf2f(unsigned short u) {
    return __uint_as_float(((unsigned int)u) << 16);
}

// ---- weights fp32 -> bf16 (768*256 + 256*256 = 262144 elems) ----
__global__ __launch_bounds__(256) void conv_w(
    const float* __restrict__ Wq, const float* __restrict__ Wp,
    unsigned short* __restrict__ out)
{
    int i = blockIdx.x * 256 + threadIdx.x;
    float v = (i < 196608) ? Wq[i] : Wp[i - 196608];
    out[i] = f2bf(v);
}

// ---- x [b][256][16384] fp32 -> xT [b*16384][256] bf16 ----
__global__ __launch_bounds__(256) void conv_xt(
    const float* __restrict__ xs, unsigned short* __restrict__ xT)
{
    __shared__ float tile[64][65];
    const int t = threadIdx.x;
    const int p0 = blockIdx.x * 64, c0 = blockIdx.y * 64;
    const float* xb = xs + (size_t)blockIdx.z * CHW_;
    unsigned short* xTb = xT + (size_t)blockIdx.z * HW_ * 256;
    {
        const int cl = t >> 4, pl = (t & 15) * 4;
        #pragma unroll
        for (int i = 0; i < 4; ++i) {
            float4 v = *reinterpret_cast<const float4*>(
                xb + (size_t)(c0 + cl + i * 16) * HW_ + p0 + pl);
            tile[cl + i * 16][pl + 0] = v.x;
            tile[cl + i * 16][pl + 1] = v.y;
            tile[cl + i * 16][pl + 2] = v.z;
            tile[cl + i * 16][pl + 3] = v.w;
        }
    }
    __syncthreads();
    #pragma unroll
    for (int i = 0; i < 2; ++i) {
        int chunk = i * 256 + t;
        int pr = chunk >> 3, c8 = (chunk & 7) * 8;
        short8 o;
        #pragma unroll
        for (int j = 0; j < 8; ++j)
            o[j] = (short)f2bf(tile[c8 + j][pr]);
        *reinterpret_cast<short8*>(xTb + (size_t)(p0 + pr) * 256 + c0 + c8) = o;
    }
}

// ---- bf16 MFMA GEMM: C[b][m][n] = sum_k A[m][k] * Bt[b*16384+n][k], K=256 --
// 128x128 tile, 4 waves (2x2), 4x4 frags of 16x16x32, fp32 accum.
// BF16OUT=1: LDS-transpose epilogue, bf16 coalesced stores.
template<int BF16OUT>
__global__ __launch_bounds__(256) void gemm_bf16(
    const unsigned short* __restrict__ A,   // [M][256] bf16
    const unsigned short* __restrict__ Bt,  // [N][256] bf16
    void* __restrict__ Cv,                  // [G][M][16384]
    size_t strideBatch)                     // = M*16384
{
    __shared__ __align__(16) char smem[BF16OUT ? 16896 : 16384];
    unsigned short* Asm = (unsigned short*)smem;
    unsigned short* Bsm = (unsigned short*)(smem + 8192);

    const int t = threadIdx.x;
    const int lane = t & 63, wid = t >> 6;
    const int m0 = blockIdx.y * 128, n0 = blockIdx.x * 128;
    const int nb = n0 >> 14, nloc0 = n0 & 16383;
    const int wr = wid >> 1, wc = wid & 1;
    const int l15 = lane & 15, l4 = lane >> 4;

    // staging sources: chunk u = i*256 + t holds logical (r=u>>2, c=cs^g(r))
    const unsigned short* srcA[2];
    const unsigned short* srcB[2];
    #pragma unroll
    for (int i = 0; i < 2; ++i) {
        int u = i * 256 + t;
        int r = u >> 2, cs = u & 3;
        int c = cs ^ ((r ^ (r >> 2)) & 3);
        srcA[i] = A  + (size_t)(m0 + r) * 256 + c * 8;
        srcB[i] = Bt + (size_t)(n0 + r) * 256 + c * 8;
    }

    // fragment read chunk indices (swizzled), loop-invariant
    int ar[4], br[4];
    #pragma unroll
    for (int i = 0; i < 4; ++i) {
        int rm = wr * 64 + i * 16 + l15;
        ar[i] = rm * 4 + (l4 ^ ((rm ^ (rm >> 2)) & 3));
        int rn = wc * 64 + i * 16 + l15;
        br[i] = rn * 4 + (l4 ^ ((rn ^ (rn >> 2)) & 3));
    }

    f32x4 acc[4][4];
    #pragma unroll
    for (int i = 0; i < 4; ++i)
        #pragma unroll
        for (int j = 0; j < 4; ++j)
            acc[i][j] = (f32x4){0.f, 0.f, 0.f, 0.f};

    const short8* Ab = (const short8*)Asm;
    const short8* Bb = (const short8*)Bsm;

    for (int k0 = 0; k0 < 256; k0 += 32) {
        __syncthreads();
        #pragma unroll
        for (int i = 0; i < 2; ++i) {
            __builtin_amdgcn_global_load_lds(
                (const __attribute__((address_space(1))) void*)(srcA[i] + k0),
                (__attribute__((address_space(3))) void*)(smem + i * 4096 + wid * 1024),
                16, 0, 0);
            __builtin_amdgcn_global_load_lds(
                (const __attribute__((address_space(1))) void*)(srcB[i] + k0),
                (__attribute__((address_space(3))) void*)(smem + 8192 + i * 4096 + wid * 1024),
                16, 0, 0);
        }
        __syncthreads();
        short8 af[4], bf[4];
        #pragma unroll
        for (int i = 0; i < 4; ++i) { af[i] = Ab[ar[i]]; bf[i] = Bb[br[i]]; }
        #pragma unroll
        for (int am = 0; am < 4; ++am)
            #pragma unroll
            for (int bn = 0; bn < 4; ++bn)
                acc[am][bn] = __builtin_amdgcn_mfma_f32_16x16x32_bf16(
                    af[am], bf[bn], acc[am][bn], 0, 0, 0);
    }

    // C/D frag layout: col = lane&15, row = (lane>>4)*4 + reg
    if (BF16OUT) {
        unsigned short* Co = (unsigned short*)Cv + (size_t)nb * strideBatch + nloc0;
        float* ep = (float*)smem;          // [32][132]
        const int rr = t >> 3, c0 = (t & 7) * 16;
        #pragma unroll
        for (int am = 0; am < 4; ++am) {
            __syncthreads();
            #pragma unroll
            for (int q = 0; q < 4; ++q)
                #pragma unroll
                for (int bn = 0; bn < 4; ++bn)
                    ep[(wr * 16 + l4 * 4 + q) * 132 + wc * 64 + bn * 16 + l15] =
                        acc[am][bn][q];
            __syncthreads();
            short8 o0, o1;
            #pragma unroll
            for (int j = 0; j < 8; ++j) {
                o0[j] = (short)f2bf(ep[rr * 132 + c0 + j]);
                o1[j] = (short)f2bf(ep[rr * 132 + c0 + 8 + j]);
            }
            int m = m0 + (rr >> 4) * 64 + am * 16 + (rr & 15);
            unsigned short* p = Co + (size_t)m * 16384 + c0;
            *reinterpret_cast<short8*>(p) = o0;
            *reinterpret_cast<short8*>(p + 8) = o1;
        }
    } else {
        float* Co = (float*)Cv + (size_t)nb * strideBatch + nloc0;
        #pragma unroll
        for (int am = 0; am < 4; ++am)
            #pragma unroll
            for (int q = 0; q < 4; ++q) {
                int m = m0 + wr * 64 + am * 16 + l4 * 4 + q;
                #pragma unroll
                for (int bn = 0; bn < 4; ++bn)
                    Co[(size_t)m * 16384 + wc * 64 + bn * 16 + l15] =
                        acc[am][bn][q];
            }
    }
}

// ---- depthwise 3x3 (SAME, zero pad), bf16 in -> bf16 windowed out ----
__global__ __launch_bounds__(256) void dwconv_win(
    const unsigned short* __restrict__ qkv,  // [G][768][16384] bf16
    const float* __restrict__ Wdw,           // [768][9]
    unsigned short* __restrict__ dww)        // [G][1024][768][16] bf16
{
    const int t   = threadIdx.x;
    const int iw  = t & 31;
    const int chl = t >> 5;
    const int wyl = blockIdx.x;
    const int ch  = blockIdx.y * 8 + chl;
    const int bz  = blockIdx.z;

    float w[9];
    #pragma unroll
    for (int i = 0; i < 9; ++i) w[i] = Wdw[ch * 9 + i];

    float h[6][6];
    const unsigned short* plane = qkv + (size_t)(bz * 768 + ch) * HW_;
    #pragma unroll
    for (int r = 0; r < 6; ++r) {
        int gy = wyl * 4 - 1 + r;
        bool vy = (gy >= 0 && gy < 128);
        const unsigned short* rp = plane + (size_t)gy * 128;
        #pragma unroll
        for (int c = 0; c < 6; ++c) {
            int gx = iw * 4 - 1 + c;
            h[r][c] = (vy && gx >= 0 && gx < 128) ? bf2f(rp[gx]) : 0.f;
        }
    }

    unsigned short* outp =
        dww + ((size_t)(bz * 1024 + wyl * 32 + iw) * 768 + ch) * 16;
    short8 o0, o1;
    #pragma unroll
    for (int py = 0; py < 4; ++py) {
        #pragma unroll
        for (int px = 0; px < 4; ++px) {
            float s = 0.f;
            #pragma unroll
            for (int dy = 0; dy < 3; ++dy)
                #pragma unroll
                for (int dx = 0; dx < 3; ++dx)
                    s += h[py + dy][px + dx] * w[dy * 3 + dx];
            int e = py * 4 + px;
            if (e < 8) o0[e] = (short)f2bf(s); else o1[e - 8] = (short)f2bf(s);
        }
    }
    *reinterpret_cast<short8*>(outp) = o0;
    *reinterpret_cast<short8*>(outp + 8) = o1;
}

// ---- per-window channel attention (vectorized LDS) ----
// Thread t owns channel t (head = t>>5, d = t&31). q row loaded from global
// to regs; k,v rows staged in LDS padded to 20 floats (80B, 16B-aligned).
__global__ __launch_bounds__(256) void attn2(
    const unsigned short* __restrict__ dww,  // [G][1024][768][16] bf16
    const float* __restrict__ temp,          // [8]
    unsigned short* __restrict__ attnT)      // [G*16384][256]
{
    __shared__ float kv[512 * 20];   // rows 0..255 k (normed), 256..511 v
    const int t   = threadIdx.x;
    const int iw  = blockIdx.x;
    const int wyl = blockIdx.y;
    const int bz  = blockIdx.z;
    const int win = bz * 1024 + wyl * 32 + iw;
    const unsigned short* src = dww + (size_t)win * 12288;

    // load q (ch t), k (ch 256+t), v (ch 512+t) rows: 32B each, coalesced
    float q[16], kr[16], vr[16];
    {
        short8 a0 = *reinterpret_cast<const short8*>(src + t * 16);
        short8 a1 = *reinterpret_cast<const short8*>(src + t * 16 + 8);
        short8 b0 = *reinterpret_cast<const short8*>(src + (256 + t) * 16);
        short8 b1 = *reinterpret_cast<const short8*>(src + (256 + t) * 16 + 8);
        short8 c0 = *reinterpret_cast<const short8*>(src + (512 + t) * 16);
        short8 c1 = *reinterpret_cast<const short8*>(src + (512 + t) * 16 + 8);
        #pragma unroll
        for (int j = 0; j < 8; ++j) {
            q[j]      = bf2f((unsigned short)a0[j]);
            q[8 + j]  = bf2f((unsigned short)a1[j]);
            kr[j]     = bf2f((unsigned short)b0[j]);
            kr[8 + j] = bf2f((unsigned short)b1[j]);
            vr[j]     = bf2f((unsigned short)c0[j]);
            vr[8 + j] = bf2f((unsigned short)c1[j]);
        }
    }

    // l2norm q and k in registers
    {
        float sq = 0.f, sk = 0.f;
        #pragma unroll
        for (int e = 0; e < 16; ++e) { sq += q[e] * q[e]; sk += kr[e] * kr[e]; }
        float cq = 1.0f / fmaxf(sqrtf(sq), 1e-12f);
        float ck = 1.0f / fmaxf(sqrtf(sk), 1e-12f);
        #pragma unroll
        for (int e = 0; e < 16; ++e) { q[e] *= cq; kr[e] *= ck; }
    }

    // stage k (normed) and v to LDS, b128 writes
    {
        float* kp = &kv[t * 20];
        float* vp = &kv[(256 + t) * 20];
        #pragma unroll
        for (int j = 0; j < 4; ++j) {
            *reinterpret_cast<float4*>(kp + j * 4) =
                make_float4(kr[j*4], kr[j*4+1], kr[j*4+2], kr[j*4+3]);
            *reinterpret_cast<float4*>(vp + j * 4) =
                make_float4(vr[j*4], vr[j*4+1], vr[j*4+2], vr[j*4+3]);
        }
    }
    __syncthreads();

    const int head = t >> 5;
    const float tmpv = temp[head];
    const float* kb = &kv[(head * 32) * 20];
    const float* vb = &kv[(256 + head * 32) * 20];

    // QK^T row: 32 dots over e=16, k rows broadcast per head
    float lg[32];
    float mx = -1e30f;
    #pragma unroll
    for (int f = 0; f < 32; ++f) {
        float s = 0.f;
        #pragma unroll
        for (int j = 0; j < 4; ++j) {
            float4 k4 = *reinterpret_cast<const float4*>(kb + f * 20 + j * 4);
            s += q[j*4] * k4.x + q[j*4+1] * k4.y + q[j*4+2] * k4.z + q[j*4+3] * k4.w;
        }
        s *= tmpv;
        lg[f] = s;
        mx = fmaxf(mx, s);
    }
    float sum = 0.f;
    #pragma unroll
    for (int f = 0; f < 32; ++f) { lg[f] = __expf(lg[f] - mx); sum += lg[f]; }
    const float inv = 1.0f / sum;

    // PV: o[e] = sum_f p[f] * v[f][e]
    float o[16];
    #pragma unroll
    for (int e = 0; e < 16; ++e) o[e] = 0.f;
    #pragma unroll
    for (int f = 0; f < 32; ++f) {
        float p = lg[f];
        #pragma unroll
        for (int j = 0; j < 4; ++j) {
            float4 v4 = *reinterpret_cast<const float4*>(vb + f * 20 + j * 4);
            o[j*4]   += p * v4.x; o[j*4+1] += p * v4.y;
            o[j*4+2] += p * v4.z; o[j*4+3] += p * v4.w;
        }
    }

    #pragma unroll
    for (int e = 0; e < 16; ++e) {
        int py = e >> 2, px = e & 3;
        size_t pl = (size_t)bz * HW_ + (wyl * 4 + py) * 128 + iw * 4 + px;
        attnT[pl * 256 + t] = f2bf(o[e] * inv);
    }
}

extern "C" void kernel_launch(void* const* d_in, const int* in_sizes, int n_in,
                              void* d_out, int out_size, void* d_ws, size_t ws_size,
                              hipStream_t stream) {
    const float* x     = (const float*)d_in[0];
    const float* Wqkv  = (const float*)d_in[1];
    const float* Wdw   = (const float*)d_in[2];
    const float* temp  = (const float*)d_in[3];
    const float* Wproj = (const float*)d_in[4];
    float* out = (float*)d_out;

    unsigned short* Wb = (unsigned short*)d_ws;        // 262144 bf16
    const size_t offW = 262144 * 2;

    // per-batch buffer bytes
    const size_t xtB  = (size_t)HW_ * 256 * 2;         // 8 MiB
    const size_t qkvB = (size_t)768 * HW_ * 2;         // 24 MiB
    const size_t dwwB = (size_t)1024 * 768 * 16 * 2;   // 24 MiB
    const size_t atB  = (size_t)HW_ * 256 * 2;         // 8 MiB
    const size_t perB = xtB + qkvB + dwwB + atB;       // 64 MiB

    int G = 8;
    while (G > 1 && offW + (size_t)G * perB > ws_size) G >>= 1;

    unsigned short* xT    = (unsigned short*)((char*)d_ws + offW);
    unsigned short* qkv   = (unsigned short*)((char*)d_ws + offW + (size_t)G * xtB);
    unsigned short* dww   = (unsigned short*)((char*)d_ws + offW + (size_t)G * (xtB + qkvB));
    unsigned short* attnT = (unsigned short*)((char*)d_ws + offW + (size_t)G * (xtB + qkvB + dwwB));

    conv_w<<<1024, 256, 0, stream>>>(Wqkv, Wproj, Wb);

    for (int b0 = 0; b0 < 8; b0 += G) {
        conv_xt<<<dim3(HW_ / 64, 4, G), 256, 0, stream>>>(
            x + (size_t)b0 * CHW_, xT);

        gemm_bf16<1><<<dim3(G * 128, 6), 256, 0, stream>>>(
            Wb, xT, qkv, (size_t)768 * HW_);

        dwconv_win<<<dim3(32, 96, G), 256, 0, stream>>>(
            qkv, Wdw, dww);

        attn2<<<dim3(32, 32, G), 256, 0, stream>>>(
            dww, temp, attnT);

        gemm_bf16<0><<<dim3(G * 128, 2), 256, 0, stream>>>(
            Wb + 196608, attnT, out + (size_t)b0 * CHW_, (size_t)CHW_);
    }
}

// Round 6
// 394.204 us; speedup vs baseline: 5.3978x; 1.2223x over previous
//
#include <hip/hip_runtime.h>
#include <math.h>

// Channel attention (XCA-style). Round 6: shuffle-vectorized dwconv.
// b=8, c=256, H=W=128, heads=8, d=32, ps=4 -> nh=nw=32, e=16.
// Per group of G batches:
//   conv_xt : x fp32 [b][c][p] -> xT bf16 [b*p][256]
//   K1 gemm<bf16out>: qkv = Wqkv_b @ xT^T -> bf16 [b][768][16384]
//   K2 dwconv_win: depthwise 3x3 -> bf16 dww[b][win][768][16]
//       (ushort4 row loads + lane shuffles for halo; 6 loads/thread)
//   K3 attn2: l2norm + 32x32 channel attn + PV -> attnT bf16 [b*p][256]
//   K4 gemm<f32out>: out = Wproj_b @ attnT^T -> fp32 [b][256][16384]

#define HW_ (128*128)
#define CHW_ (256*128*128)

typedef __attribute__((ext_vector_type(8))) short short8;
typedef __attribute__((ext_vector_type(4))) float f32x4;

static __device__ __forceinline__ unsigned short f2bf(float f) {
    unsigned int u = __float_as_uint(f);
    unsigned int r = (u + 0x7fffu + ((u >> 16) & 1u)) >> 16;   // RNE
    return (unsigned short)r;
}
static __device__ __forceinline__ float bf2f(unsigned short u) {
    return __uint_as_float(((unsigned int)u) << 16);
}

// ---- weights fp32 -> bf16 (768*256 + 256*256 = 262144 elems) ----
__global__ __launch_bounds__(256) void conv_w(
    const float* __restrict__ Wq, const float* __restrict__ Wp,
    unsigned short* __restrict__ out)
{
    int i = blockIdx.x * 256 + threadIdx.x;
    float v = (i < 196608) ? Wq[i] : Wp[i - 196608];
    out[i] = f2bf(v);
}

// ---- x [b][256][16384] fp32 -> xT [b*16384][256] bf16 ----
__global__ __launch_bounds__(256) void conv_xt(
    const float* __restrict__ xs, unsigned short* __restrict__ xT)
{
    __shared__ float tile[64][65];
    const int t = threadIdx.x;
    const int p0 = blockIdx.x * 64, c0 = blockIdx.y * 64;
    const float* xb = xs + (size_t)blockIdx.z * CHW_;
    unsigned short* xTb = xT + (size_t)blockIdx.z * HW_ * 256;
    {
        const int cl = t >> 4, pl = (t & 15) * 4;
        #pragma unroll
        for (int i = 0; i < 4; ++i) {
            float4 v = *reinterpret_cast<const float4*>(
                xb + (size_t)(c0 + cl + i * 16) * HW_ + p0 + pl);
            tile[cl + i * 16][pl + 0] = v.x;
            tile[cl + i * 16][pl + 1] = v.y;
            tile[cl + i * 16][pl + 2] = v.z;
            tile[cl + i * 16][pl + 3] = v.w;
        }
    }
    __syncthreads();
    #pragma unroll
    for (int i = 0; i < 2; ++i) {
        int chunk = i * 256 + t;
        int pr = chunk >> 3, c8 = (chunk & 7) * 8;
        short8 o;
        #pragma unroll
        for (int j = 0; j < 8; ++j)
            o[j] = (short)f2bf(tile[c8 + j][pr]);
        *reinterpret_cast<short8*>(xTb + (size_t)(p0 + pr) * 256 + c0 + c8) = o;
    }
}

// ---- bf16 MFMA GEMM: C[b][m][n] = sum_k A[m][k] * Bt[b*16384+n][k], K=256 --
// 128x128 tile, 4 waves (2x2), 4x4 frags of 16x16x32, fp32 accum.
// BF16OUT=1: LDS-transpose epilogue, bf16 coalesced stores.
template<int BF16OUT>
__global__ __launch_bounds__(256) void gemm_bf16(
    const unsigned short* __restrict__ A,   // [M][256] bf16
    const unsigned short* __restrict__ Bt,  // [N][256] bf16
    void* __restrict__ Cv,                  // [G][M][16384]
    size_t strideBatch)                     // = M*16384
{
    __shared__ __align__(16) char smem[BF16OUT ? 16896 : 16384];
    unsigned short* Asm = (unsigned short*)smem;
    unsigned short* Bsm = (unsigned short*)(smem + 8192);

    const int t = threadIdx.x;
    const int lane = t & 63, wid = t >> 6;
    const int m0 = blockIdx.y * 128, n0 = blockIdx.x * 128;
    const int nb = n0 >> 14, nloc0 = n0 & 16383;
    const int wr = wid >> 1, wc = wid & 1;
    const int l15 = lane & 15, l4 = lane >> 4;

    // staging sources: chunk u = i*256 + t holds logical (r=u>>2, c=cs^g(r))
    const unsigned short* srcA[2];
    const unsigned short* srcB[2];
    #pragma unroll
    for (int i = 0; i < 2; ++i) {
        int u = i * 256 + t;
        int r = u >> 2, cs = u & 3;
        int c = cs ^ ((r ^ (r >> 2)) & 3);
        srcA[i] = A  + (size_t)(m0 + r) * 256 + c * 8;
        srcB[i] = Bt + (size_t)(n0 + r) * 256 + c * 8;
    }

    // fragment read chunk indices (swizzled), loop-invariant
    int ar[4], br[4];
    #pragma unroll
    for (int i = 0; i < 4; ++i) {
        int rm = wr * 64 + i * 16 + l15;
        ar[i] = rm * 4 + (l4 ^ ((rm ^ (rm >> 2)) & 3));
        int rn = wc * 64 + i * 16 + l15;
        br[i] = rn * 4 + (l4 ^ ((rn ^ (rn >> 2)) & 3));
    }

    f32x4 acc[4][4];
    #pragma unroll
    for (int i = 0; i < 4; ++i)
        #pragma unroll
        for (int j = 0; j < 4; ++j)
            acc[i][j] = (f32x4){0.f, 0.f, 0.f, 0.f};

    const short8* Ab = (const short8*)Asm;
    const short8* Bb = (const short8*)Bsm;

    for (int k0 = 0; k0 < 256; k0 += 32) {
        __syncthreads();
        #pragma unroll
        for (int i = 0; i < 2; ++i) {
            __builtin_amdgcn_global_load_lds(
                (const __attribute__((address_space(1))) void*)(srcA[i] + k0),
                (__attribute__((address_space(3))) void*)(smem + i * 4096 + wid * 1024),
                16, 0, 0);
            __builtin_amdgcn_global_load_lds(
                (const __attribute__((address_space(1))) void*)(srcB[i] + k0),
                (__attribute__((address_space(3))) void*)(smem + 8192 + i * 4096 + wid * 1024),
                16, 0, 0);
        }
        __syncthreads();
        short8 af[4], bf[4];
        #pragma unroll
        for (int i = 0; i < 4; ++i) { af[i] = Ab[ar[i]]; bf[i] = Bb[br[i]]; }
        #pragma unroll
        for (int am = 0; am < 4; ++am)
            #pragma unroll
            for (int bn = 0; bn < 4; ++bn)
                acc[am][bn] = __builtin_amdgcn_mfma_f32_16x16x32_bf16(
                    af[am], bf[bn], acc[am][bn], 0, 0, 0);
    }

    // C/D frag layout: col = lane&15, row = (lane>>4)*4 + reg
    if (BF16OUT) {
        unsigned short* Co = (unsigned short*)Cv + (size_t)nb * strideBatch + nloc0;
        float* ep = (float*)smem;          // [32][132]
        const int rr = t >> 3, c0 = (t & 7) * 16;
        #pragma unroll
        for (int am = 0; am < 4; ++am) {
            __syncthreads();
            #pragma unroll
            for (int q = 0; q < 4; ++q)
                #pragma unroll
                for (int bn = 0; bn < 4; ++bn)
                    ep[(wr * 16 + l4 * 4 + q) * 132 + wc * 64 + bn * 16 + l15] =
                        acc[am][bn][q];
            __syncthreads();
            short8 o0, o1;
            #pragma unroll
            for (int j = 0; j < 8; ++j) {
                o0[j] = (short)f2bf(ep[rr * 132 + c0 + j]);
                o1[j] = (short)f2bf(ep[rr * 132 + c0 + 8 + j]);
            }
            int m = m0 + (rr >> 4) * 64 + am * 16 + (rr & 15);
            unsigned short* p = Co + (size_t)m * 16384 + c0;
            *reinterpret_cast<short8*>(p) = o0;
            *reinterpret_cast<short8*>(p + 8) = o1;
        }
    } else {
        float* Co = (float*)Cv + (size_t)nb * strideBatch + nloc0;
        #pragma unroll
        for (int am = 0; am < 4; ++am)
            #pragma unroll
            for (int q = 0; q < 4; ++q) {
                int m = m0 + wr * 64 + am * 16 + l4 * 4 + q;
                #pragma unroll
                for (int bn = 0; bn < 4; ++bn)
                    Co[(size_t)m * 16384 + wc * 64 + bn * 16 + l15] =
                        acc[am][bn][q];
            }
    }
}

// ---- depthwise 3x3 (SAME, zero pad), bf16 in -> bf16 windowed out ----
// Thread (ch, iw) owns 4 aligned pixels/row (ushort4 load); halo columns
// come from lane shuffles. Cross-channel shuffle at iw=0/31 is zeroed by
// the image border, so it is harmless.
__global__ __launch_bounds__(256) void dwconv_win(
    const unsigned short* __restrict__ qkv,  // [G][768][16384] bf16
    const float* __restrict__ Wdw,           // [768][9]
    unsigned short* __restrict__ dww)        // [G][1024][768][16] bf16
{
    const int t    = threadIdx.x;
    const int lane = t & 63;
    const int iw   = t & 31;
    const int chl  = t >> 5;
    const int wyl  = blockIdx.x;
    const int ch   = blockIdx.y * 8 + chl;
    const int bz   = blockIdx.z;

    float w[9];
    #pragma unroll
    for (int i = 0; i < 9; ++i) w[i] = Wdw[ch * 9 + i];

    float h[6][6];
    const unsigned short* plane = qkv + (size_t)(bz * 768 + ch) * HW_;
    #pragma unroll
    for (int r = 0; r < 6; ++r) {
        int gy = wyl * 4 - 1 + r;
        float c0 = 0.f, c1 = 0.f, c2 = 0.f, c3 = 0.f;
        if (gy >= 0 && gy < 128) {          // block-uniform: no divergence
            ushort4 u = *reinterpret_cast<const ushort4*>(
                plane + (size_t)gy * 128 + iw * 4);
            c0 = bf2f(u.x); c1 = bf2f(u.y); c2 = bf2f(u.z); c3 = bf2f(u.w);
        }
        float lf = __shfl(c3, (lane + 63) & 63);
        float rt = __shfl(c0, (lane + 1) & 63);
        h[r][0] = (iw == 0)  ? 0.f : lf;
        h[r][1] = c0; h[r][2] = c1; h[r][3] = c2; h[r][4] = c3;
        h[r][5] = (iw == 31) ? 0.f : rt;
    }

    unsigned short* outp =
        dww + ((size_t)(bz * 1024 + wyl * 32 + iw) * 768 + ch) * 16;
    short8 o0, o1;
    #pragma unroll
    for (int py = 0; py < 4; ++py) {
        #pragma unroll
        for (int px = 0; px < 4; ++px) {
            float s = 0.f;
            #pragma unroll
            for (int dy = 0; dy < 3; ++dy)
                #pragma unroll
                for (int dx = 0; dx < 3; ++dx)
                    s += h[py + dy][px + dx] * w[dy * 3 + dx];
            int e = py * 4 + px;
            if (e < 8) o0[e] = (short)f2bf(s); else o1[e - 8] = (short)f2bf(s);
        }
    }
    *reinterpret_cast<short8*>(outp) = o0;
    *reinterpret_cast<short8*>(outp + 8) = o1;
}

// ---- per-window channel attention (vectorized LDS) ----
// Thread t owns channel t (head = t>>5, d = t&31). q row loaded from global
// to regs; k,v rows staged in LDS padded to 20 floats (80B, 16B-aligned).
__global__ __launch_bounds__(256) void attn2(
    const unsigned short* __restrict__ dww,  // [G][1024][768][16] bf16
    const float* __restrict__ temp,          // [8]
    unsigned short* __restrict__ attnT)      // [G*16384][256]
{
    __shared__ float kv[512 * 20];   // rows 0..255 k (normed), 256..511 v
    const int t   = threadIdx.x;
    const int iw  = blockIdx.x;
    const int wyl = blockIdx.y;
    const int bz  = blockIdx.z;
    const int win = bz * 1024 + wyl * 32 + iw;
    const unsigned short* src = dww + (size_t)win * 12288;

    // load q (ch t), k (ch 256+t), v (ch 512+t) rows: 32B each, coalesced
    float q[16], kr[16], vr[16];
    {
        short8 a0 = *reinterpret_cast<const short8*>(src + t * 16);
        short8 a1 = *reinterpret_cast<const short8*>(src + t * 16 + 8);
        short8 b0 = *reinterpret_cast<const short8*>(src + (256 + t) * 16);
        short8 b1 = *reinterpret_cast<const short8*>(src + (256 + t) * 16 + 8);
        short8 c0 = *reinterpret_cast<const short8*>(src + (512 + t) * 16);
        short8 c1 = *reinterpret_cast<const short8*>(src + (512 + t) * 16 + 8);
        #pragma unroll
        for (int j = 0; j < 8; ++j) {
            q[j]      = bf2f((unsigned short)a0[j]);
            q[8 + j]  = bf2f((unsigned short)a1[j]);
            kr[j]     = bf2f((unsigned short)b0[j]);
            kr[8 + j] = bf2f((unsigned short)b1[j]);
            vr[j]     = bf2f((unsigned short)c0[j]);
            vr[8 + j] = bf2f((unsigned short)c1[j]);
        }
    }

    // l2norm q and k in registers
    {
        float sq = 0.f, sk = 0.f;
        #pragma unroll
        for (int e = 0; e < 16; ++e) { sq += q[e] * q[e]; sk += kr[e] * kr[e]; }
        float cq = 1.0f / fmaxf(sqrtf(sq), 1e-12f);
        float ck = 1.0f / fmaxf(sqrtf(sk), 1e-12f);
        #pragma unroll
        for (int e = 0; e < 16; ++e) { q[e] *= cq; kr[e] *= ck; }
    }

    // stage k (normed) and v to LDS, b128 writes
    {
        float* kp = &kv[t * 20];
        float* vp = &kv[(256 + t) * 20];
        #pragma unroll
        for (int j = 0; j < 4; ++j) {
            *reinterpret_cast<float4*>(kp + j * 4) =
                make_float4(kr[j*4], kr[j*4+1], kr[j*4+2], kr[j*4+3]);
            *reinterpret_cast<float4*>(vp + j * 4) =
                make_float4(vr[j*4], vr[j*4+1], vr[j*4+2], vr[j*4+3]);
        }
    }
    __syncthreads();

    const int head = t >> 5;
    const float tmpv = temp[head];
    const float* kb = &kv[(head * 32) * 20];
    const float* vb = &kv[(256 + head * 32) * 20];

    // QK^T row: 32 dots over e=16, k rows broadcast per head
    float lg[32];
    float mx = -1e30f;
    #pragma unroll
    for (int f = 0; f < 32; ++f) {
        float s = 0.f;
        #pragma unroll
        for (int j = 0; j < 4; ++j) {
            float4 k4 = *reinterpret_cast<const float4*>(kb + f * 20 + j * 4);
            s += q[j*4] * k4.x + q[j*4+1] * k4.y + q[j*4+2] * k4.z + q[j*4+3] * k4.w;
        }
        s *= tmpv;
        lg[f] = s;
        mx = fmaxf(mx, s);
    }
    float sum = 0.f;
    #pragma unroll
    for (int f = 0; f < 32; ++f) { lg[f] = __expf(lg[f] - mx); sum += lg[f]; }
    const float inv = 1.0f / sum;

    // PV: o[e] = sum_f p[f] * v[f][e]
    float o[16];
    #pragma unroll
    for (int e = 0; e < 16; ++e) o[e] = 0.f;
    #pragma unroll
    for (int f = 0; f < 32; ++f) {
        float p = lg[f];
        #pragma unroll
        for (int j = 0; j < 4; ++j) {
            float4 v4 = *reinterpret_cast<const float4*>(vb + f * 20 + j * 4);
            o[j*4]   += p * v4.x; o[j*4+1] += p * v4.y;
            o[j*4+2] += p * v4.z; o[j*4+3] += p * v4.w;
        }
    }

    #pragma unroll
    for (int e = 0; e < 16; ++e) {
        int py = e >> 2, px = e & 3;
        size_t pl = (size_t)bz * HW_ + (wyl * 4 + py) * 128 + iw * 4 + px;
        attnT[pl * 256 + t] = f2bf(o[e] * inv);
    }
}

extern "C" void kernel_launch(void* const* d_in, const int* in_sizes, int n_in,
                              void* d_out, int out_size, void* d_ws, size_t ws_size,
                              hipStream_t stream) {
    const float* x     = (const float*)d_in[0];
    const float* Wqkv  = (const float*)d_in[1];
    const float* Wdw   = (const float*)d_in[2];
    const float* temp  = (const float*)d_in[3];
    const float* Wproj = (const float*)d_in[4];
    float* out = (float*)d_out;

    unsigned short* Wb = (unsigned short*)d_ws;        // 262144 bf16
    const size_t offW = 262144 * 2;

    // per-batch buffer bytes
    const size_t xtB  = (size_t)HW_ * 256 * 2;         // 8 MiB
    const size_t qkvB = (size_t)768 * HW_ * 2;         // 24 MiB
    const size_t dwwB = (size_t)1024 * 768 * 16 * 2;   // 24 MiB
    const size_t atB  = (size_t)HW_ * 256 * 2;         // 8 MiB
    const size_t perB = xtB + qkvB + dwwB + atB;       // 64 MiB

    int G = 8;
    while (G > 1 && offW + (size_t)G * perB > ws_size) G >>= 1;

    unsigned short* xT    = (unsigned short*)((char*)d_ws + offW);
    unsigned short* qkv   = (unsigned short*)((char*)d_ws + offW + (size_t)G * xtB);
    unsigned short* dww   = (unsigned short*)((char*)d_ws + offW + (size_t)G * (xtB + qkvB));
    unsigned short* attnT = (unsigned short*)((char*)d_ws + offW + (size_t)G * (xtB + qkvB + dwwB));

    conv_w<<<1024, 256, 0, stream>>>(Wqkv, Wproj, Wb);

    for (int b0 = 0; b0 < 8; b0 += G) {
        conv_xt<<<dim3(HW_ / 64, 4, G), 256, 0, stream>>>(
            x + (size_t)b0 * CHW_, xT);

        gemm_bf16<1><<<dim3(G * 128, 6), 256, 0, stream>>>(
            Wb, xT, qkv, (size_t)768 * HW_);

        dwconv_win<<<dim3(32, 96, G), 256, 0, stream>>>(
            qkv, Wdw, dww);

        attn2<<<dim3(32, 32, G), 256, 0, stream>>>(
            dww, temp, attnT);

        gemm_bf16<0><<<dim3(G * 128, 2), 256, 0, stream>>>(
            Wb + 196608, attnT, out + (size_t)b0 * CHW_, (size_t)CHW_);
    }
}